// Round 1
// baseline (134.507 us; speedup 1.0000x reference)
//
#include <hip/hip_runtime.h>
#include <hip/hip_bf16.h>

// Problem constants (match reference)
#define BATCH 8192
#define KK 25
#define LL 25
#define BN_EPS 1e-5f

// ---------------------------------------------------------------------------
// Kernel A: per-column (l) batch statistics -> scale/shift for the affine
// BN transform: xn = x*scale[l] + shift[l]
//   scale[l] = gamma[l] * rsqrt(var[l]+eps)
//   shift[l] = bn_bias[l] - mean[l]*scale[l]
// ws layout: ws[0..24] = scale, ws[25..49] = shift
// ---------------------------------------------------------------------------
__global__ __launch_bounds__(256) void stats_kernel(
    const float* __restrict__ x,
    const float* __restrict__ gamma,
    const float* __restrict__ bn_bias,
    float* __restrict__ ss)
{
    const int l   = blockIdx.x;      // 0..24
    const int tid = threadIdx.x;     // 0..255

    float s = 0.f, s2 = 0.f;
    for (int b = tid; b < BATCH; b += 256) {
        float v = x[b * LL + l];
        s  += v;
        s2  = fmaf(v, v, s2);
    }

    // wave (64-lane) butterfly reduce
    for (int off = 32; off > 0; off >>= 1) {
        s  += __shfl_down(s,  off);
        s2 += __shfl_down(s2, off);
    }

    __shared__ float red[8];
    const int wave = tid >> 6;
    if ((tid & 63) == 0) { red[wave] = s; red[4 + wave] = s2; }
    __syncthreads();

    if (tid == 0) {
        s  = red[0] + red[1] + red[2] + red[3];
        s2 = red[4] + red[5] + red[6] + red[7];
        const float inv_b = 1.f / (float)BATCH;
        float mean = s * inv_b;
        float var  = fmaf(s2, inv_b, -mean * mean);
        float rstd = rsqrtf(var + BN_EPS);
        float scale = rstd * gamma[l];
        ss[l]      = scale;
        ss[LL + l] = fmaf(-mean, scale, bn_bias[l]);
    }
}

// ---------------------------------------------------------------------------
// Kernel B: one thread per (b, k). Block = 256 consecutive b for one k, so
// every weight address is wave-uniform (blockIdx.y and loop counter l only)
// and should compile to s_load + v_fmac with SGPR operands.
// ---------------------------------------------------------------------------
__global__ __launch_bounds__(256) void mlp_kernel(
    const float* __restrict__ x,
    const float* __restrict__ W1, const float* __restrict__ b1,
    const float* __restrict__ W2, const float* __restrict__ b2,
    const float* __restrict__ W3, const float* __restrict__ b3,
    const float* __restrict__ W4, const float* __restrict__ b4,
    const float* __restrict__ alpha, const float* __restrict__ beta,
    const float* __restrict__ ss,
    float* __restrict__ out)
{
    __shared__ float xs[256 * LL];   // 25.6 KB: this block's 256 rows of x

    const int tid = threadIdx.x;
    const int k   = blockIdx.y;          // 0..24
    const int b0  = blockIdx.x * 256;    // first row of this chunk

    // coalesced stage of x[b0 .. b0+255][0..24] (flat copy, 6400 floats)
    const float* xsrc = x + (size_t)b0 * LL;
    #pragma unroll
    for (int i = 0; i < LL; ++i)
        xs[i * 256 + tid] = xsrc[i * 256 + tid];
    __syncthreads();

    float acc = 0.f;

    for (int l = 0; l < LL; ++l) {
        const int kl = k * LL + l;                 // wave-uniform
        const float scale = ss[l];
        const float shift = ss[LL + l];
        // stride-25 LDS read: gcd(25,32)=1 -> conflict-free
        const float xn = fmaf(xs[tid * LL + l], scale, shift);

        const float* w1  = W1 + kl * 8;
        const float* bb1 = b1 + kl * 8;
        float h1[8];
        #pragma unroll
        for (int h = 0; h < 8; ++h)
            h1[h] = fmaxf(fmaf(xn, w1[h], bb1[h]), 0.f);

        const float* w2  = W2 + kl * 64;
        const float* bb2 = b2 + kl * 8;
        float h2[8];
        #pragma unroll
        for (int i = 0; i < 8; ++i) {
            float t = bb2[i];
            #pragma unroll
            for (int h = 0; h < 8; ++h)
                t = fmaf(h1[h], w2[i * 8 + h], t);
            h2[i] = fmaxf(t, 0.f);
        }

        const float* w3  = W3 + kl * 48;
        const float* bb3 = b3 + kl * 6;
        float h3[6];
        #pragma unroll
        for (int j = 0; j < 6; ++j) {
            float t = bb3[j];
            #pragma unroll
            for (int i = 0; i < 8; ++i)
                t = fmaf(h2[i], w3[j * 8 + i], t);
            h3[j] = fmaxf(t, 0.f);
        }

        const float* w4 = W4 + kl * 6;
        float f = b4[kl];
        #pragma unroll
        for (int j = 0; j < 6; ++j)
            f = fmaf(h3[j], w4[j], f);

        acc = fmaf(alpha[l * KK + k], f, acc);
    }

    out[(size_t)(b0 + tid) * KK + k] = beta[k] + acc;
}

extern "C" void kernel_launch(void* const* d_in, const int* in_sizes, int n_in,
                              void* d_out, int out_size, void* d_ws, size_t ws_size,
                              hipStream_t stream) {
    const float* x       = (const float*)d_in[0];
    const float* gamma   = (const float*)d_in[1];
    const float* bn_bias = (const float*)d_in[2];
    const float* W1      = (const float*)d_in[3];
    const float* b1      = (const float*)d_in[4];
    const float* W2      = (const float*)d_in[5];
    const float* b2      = (const float*)d_in[6];
    const float* W3      = (const float*)d_in[7];
    const float* b3      = (const float*)d_in[8];
    const float* W4      = (const float*)d_in[9];
    const float* b4      = (const float*)d_in[10];
    const float* alpha   = (const float*)d_in[11];
    const float* beta    = (const float*)d_in[12];

    float* out = (float*)d_out;
    float* ss  = (float*)d_ws;   // 50 floats: scale[25], shift[25]

    stats_kernel<<<dim3(LL), dim3(256), 0, stream>>>(x, gamma, bn_bias, ss);

    dim3 grid(BATCH / 256, KK);
    mlp_kernel<<<grid, dim3(256), 0, stream>>>(
        x, W1, b1, W2, b2, W3, b3, W4, b4, alpha, beta, ss, out);
}